// Round 7
// baseline (362.089 us; speedup 1.0000x reference)
//
#include <hip/hip_runtime.h>
#include <hip/hip_bf16.h>
#include <math.h>

#define NNODES 4096
#define PADY   100          // y48 row stride (floats): 400B ≡ 16 mod 32 banks -> 2-way max

typedef __attribute__((ext_vector_type(8))) short short8;
typedef __attribute__((ext_vector_type(4))) float float4v;

// ---------------------------------------------------------------------------
// Inline dtype probe: 1 => fp32 inputs, 0 => bf16. Wave-uniform ballot on the
// same 64 words of adj. Validated fp32 on this harness.
// ---------------------------------------------------------------------------
__device__ __forceinline__ int probe32(const void* adjp) {
    const unsigned* aw = (const unsigned*)adjp;
    unsigned w = aw[threadIdx.x & 63];
    unsigned e = (w >> 7) & 0xffu;
    bool insane = (e >= 0xC0u) || (e <= 0x30u);
    unsigned long long m = __ballot(insane);
    return (__popcll(m) >= 16) ? 1 : 0;
}

__device__ __forceinline__ float ldf(const void* p, size_t i, int isf32) {
    return isf32 ? ((const float*)p)[i]
                 : __bfloat162float(((const __hip_bfloat16*)p)[i]);
}

__device__ __forceinline__ void ld8(float* d, const void* p, size_t e, int isf32) {
    if (isf32) {
        const float4* s = (const float4*)((const float*)p + e);
        float4 f0 = s[0], f1 = s[1];
        d[0] = f0.x; d[1] = f0.y; d[2] = f0.z; d[3] = f0.w;
        d[4] = f1.x; d[5] = f1.y; d[6] = f1.z; d[7] = f1.w;
    } else {
        const __hip_bfloat16* s = (const __hip_bfloat16*)p + e;
#pragma unroll
        for (int j = 0; j < 8; j++) d[j] = __bfloat162float(s[j]);
    }
}

// pack 8 fp32 -> short8 of bf16 (RNE via __float2bfloat16)
__device__ __forceinline__ short8 cvt8(float4 a, float4 b) {
    union { short8 v; __hip_bfloat16 h[8]; } u;
    u.h[0] = __float2bfloat16(a.x); u.h[1] = __float2bfloat16(a.y);
    u.h[2] = __float2bfloat16(a.z); u.h[3] = __float2bfloat16(a.w);
    u.h[4] = __float2bfloat16(b.x); u.h[5] = __float2bfloat16(b.y);
    u.h[6] = __float2bfloat16(b.z); u.h[7] = __float2bfloat16(b.w);
    return u.v;
}

// ---------------------------------------------------------------------------
// Kernel 0: convert X (96 x 4096) to bf16 in workspace (validated r3-r5).
// 192 blocks x 256 thr x 8 elems. bf16 inputs: plain copy.
// ---------------------------------------------------------------------------
__global__ __launch_bounds__(256) void cvt_x(
    const void* __restrict__ xv, __hip_bfloat16* __restrict__ xbf,
    const void* __restrict__ adjp)
{
    const int isf32 = probe32(adjp);
    const int i = (blockIdx.x * 256 + threadIdx.x) * 8;
    if (isf32) {
        const float* xf = (const float*)xv;
        float4 f0 = *(const float4*)(xf + i);
        float4 f1 = *(const float4*)(xf + i + 4);
        short8 v = cvt8(f0, f1);
        *(short8*)(xbf + i) = v;
    } else {
        *(uint4*)(xbf + i) = *(const uint4*)((const __hip_bfloat16*)xv + i);
    }
}

// ---------------------------------------------------------------------------
// Kernel 1 (v7): FULLY FUSED. 256 blocks x 512 thr (8 waves), 1 block/CU.
// Block owns 16 nodes n0..n0+15 and ALL 3 adjacency blocks -> it can produce
// its final out[b,o,n] with no inter-kernel traffic (yws deleted).
//   Phase 0: stage weights to LDS + zero y48.                    [barrier 1]
//   Phase 1 (GEMM): wave w covers K-segment [w*512,+512) of all 48 rows.
//     adj: per-lane global->reg fp32 stream, 2-set static prefetch.
//     X: per-lane global bf16 (xbf, L2-resident); B-frags register-reused
//     across the 3 row-tiles. NO barriers, NO LDS in the K-loop (the
//     property that kept v4-v6 out of scratch).
//   Phase 2: waves merge acc[3][6] into LDS y48 via ds_add_f32.  [barrier 2]
//   Phase 3 (epilogue): 128 (b,n) pairs x quad-split (512 thr exactly);
//     yk from LDS; sgc j-outer (640 LDS b128/thread); GLU; out.
// C/D mapping P0 (HW-validated): col(bt)=lane&15 frag, row(node)=fq*4+reg.
// ---------------------------------------------------------------------------
__global__ __launch_bounds__(512, 2) void fused_gcn(
    const void* __restrict__ adjv, const void* __restrict__ xv,
    const __hip_bfloat16* __restrict__ xbf,
    const void* __restrict__ chebv, const void* __restrict__ gcnwv,
    const void* __restrict__ gcnbv, const void* __restrict__ g1wv,
    const void* __restrict__ g1bv, const void* __restrict__ g2wv,
    const void* __restrict__ g2bv, float* __restrict__ out)
{
    __shared__ float y48[48 * PADY];                 // 19.2 KB accumulators
    __shared__ __align__(16) float gwL[12 * 780];    // 37.4 KB [t][j*12+o] pad
    __shared__ __align__(16) float cw4L[256];        // [j*4+k] padded float4
    __shared__ float w1L[216];                       // [o*18 + c*3 + kh]
    __shared__ float w2L[216];
    __shared__ float wbL[36];

    const int tid = threadIdx.x;
    const int isf32 = probe32(adjv);

    // ---- Phase 0: weights + zero ----
    for (int i = tid; i < 9216; i += 512) {
        int o = i / 768, t = (i / 64) % 12, j = i % 64;   // gcn_w flat (o,t,0,j)
        gwL[t * 780 + j * 12 + o] = ldf(gcnwv, i, isf32);
    }
    if (tid < 256) {
        int j = tid >> 2, kk = tid & 3;
        cw4L[tid] = (kk < 3) ? ldf(chebv, j * 3 + kk, isf32) : 0.f;
    }
    if (tid < 216) {
        w1L[tid] = ldf(g1wv, (size_t)tid * 3 + 1, isf32);
        w2L[tid] = ldf(g2wv, (size_t)tid * 3 + 1, isf32);
    }
    if (tid < 12) {
        wbL[tid]      = ldf(gcnbv, tid, isf32);
        wbL[12 + tid] = ldf(g1bv, tid, isf32);
        wbL[24 + tid] = ldf(g2bv, tid, isf32);
    }
    for (int i = tid; i < 48 * PADY; i += 512) y48[i] = 0.f;
    __syncthreads();                               // barrier 1

    // ---- Phase 1: GEMM ----
    const int wv = tid >> 6, ln = tid & 63, fr = ln & 15, fq = ln >> 4;
    const int n0 = blockIdx.x * 16;
    const int kk0 = wv * 512;

    float4v acc[3][6];
#pragma unroll
    for (int rt = 0; rt < 3; rt++)
#pragma unroll
        for (int ct = 0; ct < 6; ct++) acc[rt][ct] = (float4v){0.f, 0.f, 0.f, 0.f};

    const __hip_bfloat16* xb = xbf + (size_t)fr * NNODES + kk0 + fq * 8;

    if (isf32) {
        const float* ab = (const float*)adjv
                        + (size_t)(n0 + fr) * NNODES + kk0 + fq * 8;
        float4 A0[3][2], A1[3][2];
        uint4  B0[6], B1[6];

#define ALD(S, STEP) { _Pragma("unroll")                                       \
        for (int rt = 0; rt < 3; rt++) {                                       \
            const float* p = ab + (size_t)rt * ((size_t)NNODES * NNODES)       \
                           + (STEP) * 32;                                      \
            S[rt][0] = *(const float4*)p; S[rt][1] = *(const float4*)(p + 4); } }
#define BLD(S, STEP) { _Pragma("unroll")                                       \
        for (int ct = 0; ct < 6; ct++)                                         \
            S[ct] = *(const uint4*)(xb + (size_t)ct * (16 * NNODES)            \
                                    + (STEP) * 32); }
#define CMP(SA, SB) { _Pragma("unroll")                                        \
        for (int rt = 0; rt < 3; rt++) {                                       \
            short8 a = cvt8(SA[rt][0], SA[rt][1]);                             \
            _Pragma("unroll")                                                  \
            for (int ct = 0; ct < 6; ct++)                                     \
                acc[rt][ct] = __builtin_amdgcn_mfma_f32_16x16x32_bf16(         \
                    a, *(const short8*)&SB[ct], acc[rt][ct], 0, 0, 0); } }

        ALD(A0, 0); BLD(B0, 0); ALD(A1, 1); BLD(B1, 1);
        for (int s = 0; s < 16; s += 2) {
            CMP(A0, B0);
            if (s + 2 < 16) { ALD(A0, s + 2); BLD(B0, s + 2); }
            CMP(A1, B1);
            if (s + 3 < 16) { ALD(A1, s + 3); BLD(B1, s + 3); }
        }
#undef ALD
#undef BLD
#undef CMP
    } else {
        // bf16 adj path (insurance): one uint4 per (rt, step)
        const __hip_bfloat16* ab = (const __hip_bfloat16*)adjv
                                 + (size_t)(n0 + fr) * NNODES + kk0 + fq * 8;
        uint4 A0[3], A1[3], B0[6], B1[6];

#define ALDB(S, STEP) { _Pragma("unroll")                                      \
        for (int rt = 0; rt < 3; rt++)                                         \
            S[rt] = *(const uint4*)(ab + (size_t)rt * ((size_t)NNODES * NNODES)\
                                    + (STEP) * 32); }
#define BLDB(S, STEP) { _Pragma("unroll")                                      \
        for (int ct = 0; ct < 6; ct++)                                         \
            S[ct] = *(const uint4*)(xb + (size_t)ct * (16 * NNODES)            \
                                    + (STEP) * 32); }
#define CMPB(SA, SB) { _Pragma("unroll")                                       \
        for (int rt = 0; rt < 3; rt++) {                                       \
            short8 a = *(const short8*)&SA[rt];                                \
            _Pragma("unroll")                                                  \
            for (int ct = 0; ct < 6; ct++)                                     \
                acc[rt][ct] = __builtin_amdgcn_mfma_f32_16x16x32_bf16(         \
                    a, *(const short8*)&SB[ct], acc[rt][ct], 0, 0, 0); } }

        ALDB(A0, 0); BLDB(B0, 0); ALDB(A1, 1); BLDB(B1, 1);
        for (int s = 0; s < 16; s += 2) {
            CMPB(A0, B0);
            if (s + 2 < 16) { ALDB(A0, s + 2); BLDB(B0, s + 2); }
            CMPB(A1, B1);
            if (s + 3 < 16) { ALDB(A1, s + 3); BLDB(B1, s + 3); }
        }
#undef ALDB
#undef BLDB
#undef CMPB
    }

    // ---- Phase 2: merge K-segment partials in LDS ----
#pragma unroll
    for (int rt = 0; rt < 3; rt++)
#pragma unroll
        for (int ct = 0; ct < 6; ct++)
#pragma unroll
            for (int rg = 0; rg < 4; rg++)
                atomicAdd(&y48[(rt * 16 + fq * 4 + rg) * PADY + ct * 16 + fr],
                          acc[rt][ct][rg]);
    __syncthreads();                               // barrier 2

    // ---- Phase 3: epilogue (128 pairs x quad = 512 threads exactly) ----
    const int pr = tid >> 2;                       // 0..127
    const int tq = tid & 3;                        // t-quarter
    const int b  = pr >> 4;                        // 0..7
    const int nl = pr & 15;
    const int n  = n0 + nl;

    float yk[3][3];
#pragma unroll
    for (int k = 0; k < 3; k++)
#pragma unroll
        for (int i = 0; i < 3; i++)
            yk[k][i] = y48[(k * 16 + nl) * PADY + b * 12 + tq * 3 + i];

    float sg[12];
#pragma unroll
    for (int o = 0; o < 12; o++) sg[o] = 0.f;
    const float4* cw4 = (const float4*)cw4L;
    const float4* gwt0 = (const float4*)(gwL + (tq * 3 + 0) * 780);
    const float4* gwt1 = (const float4*)(gwL + (tq * 3 + 1) * 780);
    const float4* gwt2 = (const float4*)(gwL + (tq * 3 + 2) * 780);
#pragma unroll 4
    for (int j = 0; j < 64; j++) {
        float4 cw = cw4[j];
#pragma unroll
        for (int i = 0; i < 3; i++) {
            float h = fmaf(yk[0][i], cw.x, fmaf(yk[1][i], cw.y, yk[2][i] * cw.z));
            h = fmaxf(h, 0.f);
            const float4* gwt = (i == 0) ? gwt0 : (i == 1) ? gwt1 : gwt2;
            float4 g0 = gwt[j * 3], g1 = gwt[j * 3 + 1], g2 = gwt[j * 3 + 2];
            sg[0] += h * g0.x; sg[1] += h * g0.y; sg[2]  += h * g0.z; sg[3]  += h * g0.w;
            sg[4] += h * g1.x; sg[5] += h * g1.y; sg[6]  += h * g1.z; sg[7]  += h * g1.w;
            sg[8] += h * g2.x; sg[9] += h * g2.y; sg[10] += h * g2.z; sg[11] += h * g2.w;
        }
    }
    // quad reduction: all 4 lanes end with the full t-sum
#pragma unroll
    for (int o = 0; o < 12; o++) {
        sg[o] += __shfl_xor(sg[o], 1);
        sg[o] += __shfl_xor(sg[o], 2);
    }

    // GLU (dilated conv taps n-2, n, n+2; only kw=1 alive); lane owns
    // o = tq*3 .. tq*3+2
    float xa[18], xg[18];
#pragma unroll
    for (int c = 0; c < 6; c++)
#pragma unroll
        for (int kh = 0; kh < 3; kh++) {
            int m = n + 2 * kh - 2;
            bool ok = ((unsigned)m < (unsigned)NNODES);
            xa[c * 3 + kh] = ok ? ldf(xv, ((size_t)(b * 12 + c)) * NNODES + m, isf32) : 0.f;
            xg[c * 3 + kh] = ok ? ldf(xv, ((size_t)(b * 12 + c + 6)) * NNODES + m, isf32) : 0.f;
        }

#pragma unroll
    for (int i = 0; i < 3; i++) {
        const int o = tq * 3 + i;
        float av = wbL[12 + o], gv = wbL[24 + o];
#pragma unroll
        for (int q = 0; q < 18; q++) {
            av += xa[q] * w1L[o * 18 + q];
            gv += xg[q] * w2L[o * 18 + q];
        }
        float s = 1.f / (1.f + expf(-gv));
        out[((size_t)(b * 12 + o)) * NNODES + n] = av * s + sg[o] + wbL[o];
    }
}

// ---------------------------------------------------------------------------
// Fallback single kernel (only if ws too small): verified path.
// ---------------------------------------------------------------------------
__global__ __launch_bounds__(64) void fused_simple(
    const void* __restrict__ xv, const void* __restrict__ adjv,
    const void* __restrict__ chebv, const void* __restrict__ gcnwv,
    const void* __restrict__ gcnbv, const void* __restrict__ g1wv,
    const void* __restrict__ g1bv, const void* __restrict__ g2wv,
    const void* __restrict__ g2bv,
    float* __restrict__ out)
{
    __shared__ float gwL[9216];
    __shared__ float cwL[192];
    __shared__ float w1L[216];
    __shared__ float w2L[216];
    __shared__ float wbL[36];

    const int tid = threadIdx.x;
    const int isf32 = probe32(adjv);

    for (int i = tid; i < 9216; i += 64) {
        int o = i / 768, t = (i / 64) % 12, j = i % 64;
        gwL[t * 768 + j * 12 + o] = ldf(gcnwv, i, isf32);
    }
    for (int i = tid; i < 192; i += 64) cwL[i] = ldf(chebv, i, isf32);
    for (int i = tid; i < 216; i += 64) {
        w1L[i] = ldf(g1wv, (size_t)i * 3 + 1, isf32);
        w2L[i] = ldf(g2wv, (size_t)i * 3 + 1, isf32);
    }
    if (tid < 12) {
        wbL[tid]      = ldf(gcnbv, tid, isf32);
        wbL[12 + tid] = ldf(g1bv, tid, isf32);
        wbL[24 + tid] = ldf(g2bv, tid, isf32);
    }
    __syncthreads();

    const int g = blockIdx.x * 64 + tid;
    const int b = g >> 12;
    const int n = g & (NNODES - 1);

    float y[3][12];
#pragma unroll
    for (int k = 0; k < 3; k++)
#pragma unroll
        for (int t = 0; t < 12; t++) y[k][t] = 0.f;

    for (int m0 = 0; m0 < NNODES; m0 += 8) {
        float a0[8], a1[8], a2[8];
        ld8(a0, adjv, ((size_t)(0 * NNODES + n)) * NNODES + m0, isf32);
        ld8(a1, adjv, ((size_t)(1 * NNODES + n)) * NNODES + m0, isf32);
        ld8(a2, adjv, ((size_t)(2 * NNODES + n)) * NNODES + m0, isf32);
#pragma unroll
        for (int t = 0; t < 12; t++) {
            float x8[8];
            ld8(x8, xv, ((size_t)(b * 12 + t)) * NNODES + m0, isf32);
#pragma unroll
            for (int j = 0; j < 8; j++) {
                y[0][t] += a0[j] * x8[j];
                y[1][t] += a1[j] * x8[j];
                y[2][t] += a2[j] * x8[j];
            }
        }
    }

    float sg[12];
#pragma unroll
    for (int o = 0; o < 12; o++) sg[o] = wbL[o];
    for (int t = 0; t < 12; t++) {
        const float y0 = y[0][t], y1 = y[1][t], y2 = y[2][t];
        const float* gwt = gwL + t * 768;
#pragma unroll 4
        for (int j = 0; j < 64; j++) {
            float h = y0 * cwL[j * 3] + y1 * cwL[j * 3 + 1] + y2 * cwL[j * 3 + 2];
            h = fmaxf(h, 0.f);
#pragma unroll
            for (int o = 0; o < 12; o++) sg[o] += h * gwt[j * 12 + o];
        }
    }

    float xa[18], xg[18];
#pragma unroll
    for (int c = 0; c < 6; c++)
#pragma unroll
        for (int kh = 0; kh < 3; kh++) {
            int m = n + 2 * kh - 2;
            bool ok = ((unsigned)m < (unsigned)NNODES);
            xa[c * 3 + kh] = ok ? ldf(xv, ((size_t)(b * 12 + c)) * NNODES + m, isf32) : 0.f;
            xg[c * 3 + kh] = ok ? ldf(xv, ((size_t)(b * 12 + c + 6)) * NNODES + m, isf32) : 0.f;
        }

#pragma unroll
    for (int o = 0; o < 12; o++) {
        float av = wbL[12 + o], gv = wbL[24 + o];
#pragma unroll
        for (int i = 0; i < 18; i++) {
            av += xa[i] * w1L[o * 18 + i];
            gv += xg[i] * w2L[o * 18 + i];
        }
        float s = 1.f / (1.f + expf(-gv));
        out[((size_t)(b * 12 + o)) * NNODES + n] = av * s + sg[o];
    }
}

// ---------------------------------------------------------------------------
extern "C" void kernel_launch(void* const* d_in, const int* in_sizes, int n_in,
                              void* d_out, int out_size, void* d_ws, size_t ws_size,
                              hipStream_t stream)
{
    __hip_bfloat16* xbf = (__hip_bfloat16*)((char*)d_ws + 64);   // 768 KB
    const size_t need = 64 + (size_t)96 * NNODES * 2;

    if (ws_size >= need) {
        hipLaunchKernelGGL(cvt_x, dim3(192), dim3(256), 0, stream,
                           d_in[0], xbf, d_in[1]);
        hipLaunchKernelGGL(fused_gcn, dim3(NNODES / 16), dim3(512), 0, stream,
                           d_in[1], d_in[0], xbf, d_in[2], d_in[3], d_in[4],
                           d_in[5], d_in[6], d_in[7], d_in[8],
                           (float*)d_out);
    } else {
        hipLaunchKernelGGL(fused_simple, dim3(512), dim3(64), 0, stream,
                           d_in[0], d_in[1], d_in[2], d_in[3], d_in[4],
                           d_in[5], d_in[6], d_in[7], d_in[8],
                           (float*)d_out);
    }
}